// Round 6
// baseline (276.852 us; speedup 1.0000x reference)
//
#include <hip/hip_runtime.h>

// GGNN message passing, round 6: 3 dispatches, PA as 4th epilogue plane,
// conflict-free col-pack, VGPR-capped main.
//
//   adj in {0..3}. Planes: B0 = bit0(adj), B1 = bit1(adj), T = B0&B1.
//   P0 = B0@H, P1 = B1@H, PT = T@H, PA[e] = sum_j h[j][e]  (per batch)
//   m = P0(M1-M0)^T + P1(M2-M0)^T + PT(M0-M1-M2+M3)^T + PA M0^T + bias
//   (out-direction: same with adj^T and Mout.)
//
// K1 pack_adjm: blocks 0..2047 stream adj (128 MB) -> 2-bit row packs (adjP)
//   + col packs (adjPT), 8 MB each, main-tile order. Col-pack gather now goes
//   through col-major padded LDS rp2[16][68]: 16 broadcast conflict-free
//   ds_read_b128 + ~128 VALU per thread (was 64 ds_read_b32 + ~320 VALU).
//   Block 2048 converts M -> Mws bf16 [dir][4 planes][d][e], plane3 = M0.
// K2 prep_h: h -> Hws bf16 H^T tiles (4 MB) + per-chunk PA partials (no
//   atomics, no memset dispatch).
// K3 ggnn_main: barrier-free K-loop identical to round 5 (passed, absmax
//   0.75). Epilogue gains plane 3: S3[i][e] = PA[e] (summed from partials,
//   bf16) contracted against M0 by the same MFMA pattern; bias added directly.
//   __launch_bounds__(256,4): cap 128 VGPR -> guaranteed 4 blocks/CU
//   (LDS 36.9 KB also caps at 4); live-set model ~110 regs.

namespace {

typedef unsigned int  u32;
typedef unsigned short u16;
typedef __attribute__((ext_vector_type(8))) short bf16x8;
typedef __attribute__((ext_vector_type(4))) float f32x4;

constexpr int NN = 1024;
constexpr int ND = 64;

__device__ inline u16 f2bf(float x) {                  // f32 -> bf16 bits, RNE
    u32 u = __float_as_uint(x);
    return (u16)((u + 0x7FFFu + ((u >> 16) & 1u)) >> 16);
}
__device__ inline float bf2f(u16 x) { return __uint_as_float(((u32)x) << 16); }

// z bits 0,2 = indicators (rest masked off) -> u32 of 2 bf16 {0,1}. Proven r3/r5.
__device__ inline u32 oh2(u32 z) {
    return ((z & 1u) | ((z & 4u) << 14)) * 0x3F80u;
}

// ------------------------------------------------------- K1: pack + M-prep
// blocks < 2048: (b, It, Jt, s): adj rows It*256+s*64..+64, cols Jt*256..+256.
//   adjP[b][jc=Jt][it=It*4+s][u=seg][row][q]  (row-pack)
//   adjPT[b][jc=It][it=Jt*4+sc][u=s][il][jj]  (col-pack)
// block 2048: Mws[dir][4][64][64] bf16: {M1-M0, M2-M0, M0-M1-M2+M3, M0}
__global__ __launch_bounds__(256) void pack_adjm(
    const int* __restrict__ adj, const float* __restrict__ Min,
    const float* __restrict__ Mout, u32* __restrict__ adjP,
    u32* __restrict__ adjPT, u16* __restrict__ Mws)
{
    const int t = threadIdx.x;
    const int bid = blockIdx.x;
    if (bid >= 2048) {                       // M-prep block
        for (int i = t; i < 8192; i += 256) {
            const float* M = (i < 4096) ? Min : Mout;
            int idx = i & 4095;
            float m0 = M[idx], m1 = M[4096 + idx], m2 = M[8192 + idx], m3 = M[12288 + idx];
            u16* o = Mws + (size_t)(i >> 12) * 16384;
            o[idx]         = f2bf(m1 - m0);
            o[4096 + idx]  = f2bf(m2 - m0);
            o[8192 + idx]  = f2bf(m0 - m1 - m2 + m3);
            o[12288 + idx] = f2bf(m0);
        }
        return;
    }

    __shared__ u32 rp2[16][68];              // col-major [cw][row], +4 pad
    const int b = bid >> 6, It = (bid >> 4) & 3, Jt = (bid >> 2) & 3, s = bid & 3;
    const int* base = adj + ((size_t)b << 20) + (size_t)(It * 256 + s * 64) * NN + Jt * 256;

    const int row = t >> 2, seg = t & 3;
    const int* rptr = base + (size_t)row * NN + seg * 64;
    u32 w[4];
    #pragma unroll
    for (int q = 0; q < 4; ++q) {
        int4 v0 = *(const int4*)(rptr + q * 16 + 0);
        int4 v1 = *(const int4*)(rptr + q * 16 + 4);
        int4 v2 = *(const int4*)(rptr + q * 16 + 8);
        int4 v3 = *(const int4*)(rptr + q * 16 + 12);
        u32 u = (u32)(v0.x & 3) | ((u32)(v0.y & 3) << 2) | ((u32)(v0.z & 3) << 4) | ((u32)(v0.w & 3) << 6)
              | ((u32)(v1.x & 3) << 8) | ((u32)(v1.y & 3) << 10) | ((u32)(v1.z & 3) << 12) | ((u32)(v1.w & 3) << 14)
              | ((u32)(v2.x & 3) << 16) | ((u32)(v2.y & 3) << 18) | ((u32)(v2.z & 3) << 20) | ((u32)(v2.w & 3) << 22)
              | ((u32)(v3.x & 3) << 24) | ((u32)(v3.y & 3) << 26) | ((u32)(v3.z & 3) << 28) | ((u32)(v3.w & 3) << 30);
        w[q] = u;
        rp2[seg * 4 + q][row] = u;           // 2-way bank alias only (free)
    }
    u32* op = adjP + (((((size_t)b * 4 + Jt) * 16 + It * 4 + s) * 4 + seg) * 64 + row) * 4;
    *(uint4*)op = make_uint4(w[0], w[1], w[2], w[3]);
    __syncthreads();

    const int sc = t >> 6, il = t & 63;
    const int cw = sc * 4 + (il >> 4);       // 16 lanes share cw -> broadcast
    const int bp = (il & 15) * 2;
    u32 o[4];
    #pragma unroll
    for (int jj = 0; jj < 4; ++jj) {
        u32 r[16];
        *(uint4*)&r[0]  = *(const uint4*)&rp2[cw][jj * 16 + 0];
        *(uint4*)&r[4]  = *(const uint4*)&rp2[cw][jj * 16 + 4];
        *(uint4*)&r[8]  = *(const uint4*)&rp2[cw][jj * 16 + 8];
        *(uint4*)&r[12] = *(const uint4*)&rp2[cw][jj * 16 + 12];
        u32 acc = 0;
        #pragma unroll
        for (int k = 0; k < 16; ++k)
            acc += ((r[k] >> bp) & 3u) << (2 * k);   // bfe + lshl_add
        o[jj] = acc;
    }
    u32* op2 = adjPT + (((((size_t)b * 4 + It) * 16 + Jt * 4 + sc) * 4 + s) * 64 + il) * 4;
    *(uint4*)op2 = make_uint4(o[0], o[1], o[2], o[3]);
}

// ---------------------------------------------------------------- K2: prep_h
// block (b, jc): h -> Hws tile (unit u=j-octet, e) and PApart[jc][b][e].
__global__ __launch_bounds__(256) void prep_h(
    const float* __restrict__ h, u16* __restrict__ Hws, float* __restrict__ PApart)
{
    __shared__ u16 hl[256][72];
    __shared__ float red[4][64];
    const int t = threadIdx.x;
    const int b = blockIdx.x >> 2, jc = blockIdx.x & 3;
    const float* hb = h + ((size_t)b * NN + jc * 256) * ND;
    #pragma unroll
    for (int k = 0; k < 16; ++k) {
        int j = k * 16 + (t >> 4);
        int e4 = (t & 15) * 4;
        float4 v = *(const float4*)(hb + (size_t)j * ND + e4);
        *(u32*)&hl[j][e4]     = (u32)f2bf(v.x) | ((u32)f2bf(v.y) << 16);
        *(u32*)&hl[j][e4 + 2] = (u32)f2bf(v.z) | ((u32)f2bf(v.w) << 16);
    }
    __syncthreads();
    u16* ob = Hws + (size_t)(b * 4 + jc) * 2048 * 8;
    const int e = t & 63;
    float psum = 0.f;
    #pragma unroll
    for (int k = 0; k < 8; ++k) {
        int u = k * 4 + (t >> 6);
        u16 x0 = hl[u * 8 + 0][e], x1 = hl[u * 8 + 1][e], x2 = hl[u * 8 + 2][e], x3 = hl[u * 8 + 3][e];
        u16 x4 = hl[u * 8 + 4][e], x5 = hl[u * 8 + 5][e], x6 = hl[u * 8 + 6][e], x7 = hl[u * 8 + 7][e];
        psum += bf2f(x0) + bf2f(x1) + bf2f(x2) + bf2f(x3) + bf2f(x4) + bf2f(x5) + bf2f(x6) + bf2f(x7);
        u32 p0 = (u32)x0 | ((u32)x1 << 16), p1 = (u32)x2 | ((u32)x3 << 16);
        u32 p2 = (u32)x4 | ((u32)x5 << 16), p3 = (u32)x6 | ((u32)x7 << 16);
        *(uint4*)(ob + (size_t)(u * 64 + e) * 8) = make_uint4(p0, p1, p2, p3);
    }
    red[t >> 6][e] = psum;
    __syncthreads();
    if (t < 64) {
        float sum = red[0][t] + red[1][t] + red[2][t] + red[3][t];
        PApart[(size_t)(jc * 32 + b) * 64 + t] = sum;
    }
}

// ---------------------------------------------------------------- K3: main
__global__ __launch_bounds__(256, 4) void ggnn_main(
    const u32* __restrict__ adjP, const u32* __restrict__ adjPT,
    const u16* __restrict__ Hws, const u16* __restrict__ Mws,
    const float* __restrict__ PApart, const float* __restrict__ bias,
    float* __restrict__ out)
{
    __shared__ u16 Sb[16][16][72];   // per-wave slots w*4+p (p=3 -> PA plane)

    const int t = threadIdx.x;
    const int w = t >> 6;
    const int ln = t & 15, qd = (t & 63) >> 4, qd2 = qd >> 1;
    const int shamt = (qd & 1) * 16;
    const int bid = blockIdx.x;
    const int dir = bid >> 9;
    const int b = (bid >> 4) & 31, it = bid & 15;

    const u32* Adir = dir ? adjPT : adjP;
    f32x4 acc[3][4];
    #pragma unroll
    for (int p = 0; p < 3; ++p)
        #pragma unroll
        for (int nt = 0; nt < 4; ++nt) acc[p][nt] = (f32x4){0.f, 0.f, 0.f, 0.f};

    // A-words for chunk 0; rotate a prefetch of chunk jc+1 through the loop
    uint4 Ar[4];
    {
        const u32* at = Adir + (size_t)((b * 4 + 0) * 16 + it) * 1024;
        #pragma unroll
        for (int u = 0; u < 4; ++u)
            Ar[u] = *(const uint4*)(at + (u * 64 + w * 16 + ln) * 4);
    }

    #pragma unroll
    for (int jc = 0; jc < 4; ++jc) {
        const u16* ht = Hws + (size_t)(b * 4 + jc) * 16384;
        uint4 ArN[4];
        if (jc < 3) {
            const u32* at = Adir + (size_t)((b * 4 + jc + 1) * 16 + it) * 1024;
            #pragma unroll
            for (int u = 0; u < 4; ++u)
                ArN[u] = *(const uint4*)(at + (u * 64 + w * 16 + ln) * 4);
        }

        #pragma unroll
        for (int ks = 0; ks < 8; ++ks) {
            bf16x8 bf[4];
            #pragma unroll
            for (int nt = 0; nt < 4; ++nt)
                bf[nt] = *(const bf16x8*)(ht + (size_t)((ks * 4 + qd) * 64 + nt * 16 + ln) * 8);

            uint4 Q = Ar[ks >> 1];
            u32 a = (ks & 1) ? (qd2 ? Q.w : Q.z) : (qd2 ? Q.y : Q.x);
            u32 f = (a >> shamt) & 0xFFFFu;
            u32 x0 = f & 0x5555u;            // bit0 plane (classes 1,3)
            u32 x1 = (f >> 1) & 0x5555u;     // bit1 plane (classes 2,3)
            u32 xt = x0 & x1;                // class 3

            union { u32 u[4]; bf16x8 v; } A0, A1, AT;
            #pragma unroll
            for (int wd = 0; wd < 4; ++wd) {
                A0.u[wd] = oh2(x0 >> (4 * wd));
                A1.u[wd] = oh2(x1 >> (4 * wd));
                AT.u[wd] = oh2(xt >> (4 * wd));
            }
            #pragma unroll
            for (int nt = 0; nt < 4; ++nt) {
                acc[0][nt] = __builtin_amdgcn_mfma_f32_16x16x32_bf16(A0.v, bf[nt], acc[0][nt], 0, 0, 0);
                acc[1][nt] = __builtin_amdgcn_mfma_f32_16x16x32_bf16(A1.v, bf[nt], acc[1][nt], 0, 0, 0);
                acc[2][nt] = __builtin_amdgcn_mfma_f32_16x16x32_bf16(AT.v, bf[nt], acc[2][nt], 0, 0, 0);
            }
        }
        if (jc < 3) {
            #pragma unroll
            for (int u = 0; u < 4; ++u) Ar[u] = ArN[u];
        }
    }

    // P (C-layout regs) -> LDS bf16 per-wave slots; wave-internal, no barrier
    #pragma unroll
    for (int p = 0; p < 3; ++p)
        #pragma unroll
        for (int nt = 0; nt < 4; ++nt)
            #pragma unroll
            for (int r = 0; r < 4; ++r)
                Sb[w * 4 + p][qd * 4 + r][nt * 16 + ln] = f2bf(acc[p][nt][r]);

    // plane 3: S3[i][e] = PA[e] (sum of 4 per-chunk partials), constant rows
    {
        const int lane64 = t & 63;
        float paf = 0.f;
        #pragma unroll
        for (int jcp = 0; jcp < 4; ++jcp)
            paf += PApart[(size_t)(jcp * 32 + b) * 64 + lane64];
        u16 pab = f2bf(paf);
        #pragma unroll
        for (int i = 0; i < 16; ++i)
            Sb[w * 4 + 3][i][lane64] = pab;
    }

    const int dofs = dir * 64;
    f32x4 acc2[4];
    #pragma unroll
    for (int dt = 0; dt < 4; ++dt) {
        float v = bias[dofs + dt * 16 + ln];
        acc2[dt] = (f32x4){v, v, v, v};
    }
    const u16* Mb = Mws + (size_t)dir * 16384;   // [4][64][64]
    #pragma unroll
    for (int p = 0; p < 4; ++p) {
        #pragma unroll
        for (int ks2 = 0; ks2 < 2; ++ks2) {
            bf16x8 af = *(const bf16x8*)&Sb[w * 4 + p][ln][ks2 * 32 + qd * 8];
            #pragma unroll
            for (int dt = 0; dt < 4; ++dt) {
                bf16x8 mf = *(const bf16x8*)(Mb + (size_t)(p * 64 + dt * 16 + ln) * 64
                                             + ks2 * 32 + qd * 8);
                acc2[dt] = __builtin_amdgcn_mfma_f32_16x16x32_bf16(af, mf, acc2[dt], 0, 0, 0);
            }
        }
    }
    #pragma unroll
    for (int dt = 0; dt < 4; ++dt)
        #pragma unroll
        for (int r = 0; r < 4; ++r)
            out[((size_t)b * NN + it * 64 + w * 16 + qd * 4 + r) * 128
                + dofs + dt * 16 + ln] = acc2[dt][r];
}

} // namespace

extern "C" void kernel_launch(void* const* d_in, const int* in_sizes, int n_in,
                              void* d_out, int out_size, void* d_ws, size_t ws_size,
                              hipStream_t stream) {
    (void)in_sizes; (void)n_in; (void)out_size; (void)ws_size;
    const float* h    = (const float*)d_in[0];   // [32,1024,64] f32
    const int*   adj  = (const int*)d_in[1];     // [32,1024,1024] i32
    const float* Min  = (const float*)d_in[2];   // [4,64,64] f32
    const float* Mout = (const float*)d_in[3];   // [4,64,64] f32
    const float* bias = (const float*)d_in[4];   // [128] f32
    float* out = (float*)d_out;                  // [32,1024,128] f32

    char* ws = (char*)d_ws;
    u32* adjP     = (u32*)(ws + 0);              // 8 MB
    u32* adjPT    = (u32*)(ws + 8388608);        // 8 MB
    u16* Hws      = (u16*)(ws + 16777216);       // 4 MB
    float* PApart = (float*)(ws + 20971520);     // 32 KB [4][32][64]
    u16* Mws      = (u16*)(ws + 21004288);       // 64 KB [2][4][64][64]

    pack_adjm<<<2049, 256, 0, stream>>>(adj, Min, Mout, adjP, adjPT, Mws);
    prep_h<<<128, 256, 0, stream>>>(h, Hws, PApart);
    ggnn_main<<<1024, 256, 0, stream>>>(adjP, adjPT, Hws, Mws, PApart, bias, out);
}

// Round 7
// 268.382 us; speedup vs baseline: 1.0316x; 1.0316x over previous
//
#include <hip/hip_runtime.h>

// GGNN message passing, round 7: 2 dispatches (prep_all + main), pack rebuilt
// for lane-contiguous loads + byte-LDS transpose.
//
//   adj in {0..3}. Planes: B0 = bit0(adj), B1 = bit1(adj), T = B0&B1.
//   P0 = B0@H, P1 = B1@H, PT = T@H, PA[e] = sum_j h[j][e]  (per batch)
//   m = P0(M1-M0)^T + P1(M2-M0)^T + PT(M0-M1-M2+M3)^T + PA M0^T + bias
//   (out-direction: same with adj^T and Mout.)
//
// Harness-floor finding (r6 fill ordinals 115/119 gap=4): ~2 x 512MB d_ws
// poisons + 136MB d_in restore per iter ~= 200-210 us fixed. Our kernels are
// only ~60-70 us of the ~277 total. This round: pack 2x (coalesced loads:
// wave = 1KB contiguous; 4-codes->byte; dual byte-LDS; row word = 1
// ds_read_b128, col word = 4 broadcast b32 + ~180 VALU), 2 dispatch gaps
// removed, dir interleaved in low block bit for L2-shared H tiles.

namespace {

typedef unsigned int   u32;
typedef unsigned short u16;
typedef unsigned char  u8;
typedef __attribute__((ext_vector_type(8))) short bf16x8;
typedef __attribute__((ext_vector_type(4))) float f32x4;

constexpr int NN = 1024;

__device__ inline u16 f2bf(float x) {                  // f32 -> bf16 bits, RNE
    u32 u = __float_as_uint(x);
    return (u16)((u + 0x7FFFu + ((u >> 16) & 1u)) >> 16);
}
// z bits 0,2 = indicators (rest masked) -> u32 of 2 bf16 {0,1}. Proven r3/r5/r6.
__device__ inline u32 oh2(u32 z) {
    return ((z & 1u) | ((z & 4u) << 14)) * 0x3F80u;
}

// ------------------------------------------------ K1: prep_all (one dispatch)
// blocks 0..2047   : pack one 64x256 adj tile -> adjP (row words) + adjPT (col)
// blocks 2048..2303: prep_h, 128 j-rows each -> Hws bf16 H^T + PApart
// block  2304      : M planes -> Mws bf16 [dir][4][64][64]
__global__ __launch_bounds__(256) void prep_all(
    const int* __restrict__ adj, const float* __restrict__ h,
    const float* __restrict__ Min, const float* __restrict__ Mout,
    u32* __restrict__ adjP, u32* __restrict__ adjPT,
    u16* __restrict__ Hws, float* __restrict__ PApart, u16* __restrict__ Mws)
{
    __shared__ __align__(16) char sbuf[19456];
    const int t = threadIdx.x;
    const int bid = blockIdx.x;

    if (bid < 2048) {
        // ---- pack tile (b, It, Jt, s): rows It*256+s*64..+64, cols Jt*256..+256
        u8* ldsR = (u8*)sbuf;          // [64 rows][64 c4] bytes (byte = 4 codes)
        u8* ldsC = (u8*)sbuf + 4096;   // [64 c4][68 rows] transposed, 17-bank step
        const int b = bid >> 6, It = (bid >> 4) & 3, Jt = (bid >> 2) & 3, s = bid & 3;
        const int* base = adj + ((size_t)b << 20)
                        + (size_t)(It * 256 + s * 64) * NN + Jt * 256;

        #pragma unroll
        for (int k = 0; k < 16; ++k) {          // wave reads 1 KB contiguous
            int f = k * 256 + t;
            int row = f >> 6, c4 = f & 63;
            int4 v = *(const int4*)(base + row * NN + c4 * 4);
            u8 byte = (u8)((v.x & 3) | ((v.y & 3) << 2) | ((v.z & 3) << 4) | ((v.w & 3) << 6));
            ldsR[row * 64 + c4] = byte;
            ldsC[c4 * 68 + row] = byte;
        }
        __syncthreads();

        // row words: one uint4 per thread = 64 codes
        {
            int row = t >> 2, seg = t & 3;
            uint4 wv = *(const uint4*)&ldsR[row * 64 + seg * 16];
            u32* op = adjP + (((((size_t)b * 4 + Jt) * 16 + It * 4 + s) * 4 + seg) * 64 + row) * 4;
            *(uint4*)op = wv;
        }
        // col words: thread t owns column c = t; 4 words of 16 rows
        {
            int c4 = t >> 2, bp = (t & 3) * 2;
            int sc = t >> 6, il = t & 63;
            u32 o[4];
            #pragma unroll
            for (int jj = 0; jj < 4; ++jj) {
                u32 acc = 0;
                #pragma unroll
                for (int m4 = 0; m4 < 4; ++m4) {
                    u32 r = *(const u32*)&ldsC[c4 * 68 + jj * 16 + m4 * 4];
                    #pragma unroll
                    for (int m = 0; m < 4; ++m)
                        acc |= ((r >> (8 * m + bp)) & 3u) << (2 * (m4 * 4 + m));
                }
                o[jj] = acc;
            }
            u32* op2 = adjPT + (((((size_t)b * 4 + It) * 16 + Jt * 4 + sc) * 4 + s) * 64 + il) * 4;
            *(uint4*)op2 = make_uint4(o[0], o[1], o[2], o[3]);
        }
        return;
    }

    if (bid < 2304) {
        // ---- prep_h: idx -> (b, jc, half); 128 j-rows
        u16 (*hl)[72] = (u16(*)[72])sbuf;            // 18432 B
        float* red = (float*)(sbuf + 18432);         // [4][64]
        const int idx = bid - 2048;
        const int b = idx >> 3, jc = (idx >> 1) & 3, half = idx & 1;
        const float* hb = h + ((size_t)b * NN + jc * 256 + half * 128) * 64;
        #pragma unroll
        for (int k = 0; k < 8; ++k) {
            int f = k * 256 + t;
            int j = f >> 4, e4 = (f & 15) * 4;
            float4 v = *(const float4*)(hb + (size_t)j * 64 + e4);
            *(u32*)&hl[j][e4]     = (u32)f2bf(v.x) | ((u32)f2bf(v.y) << 16);
            *(u32*)&hl[j][e4 + 2] = (u32)f2bf(v.z) | ((u32)f2bf(v.w) << 16);
        }
        __syncthreads();
        u16* ob = Hws + (size_t)(b * 4 + jc) * 16384 + (size_t)half * 16 * 64 * 8;
        const int e = t & 63;
        float psum = 0.f;
        #pragma unroll
        for (int k = 0; k < 4; ++k) {
            int u = k * 4 + (t >> 6);               // local octet 0..15
            u16 x0 = hl[u * 8 + 0][e], x1 = hl[u * 8 + 1][e];
            u16 x2 = hl[u * 8 + 2][e], x3 = hl[u * 8 + 3][e];
            u16 x4 = hl[u * 8 + 4][e], x5 = hl[u * 8 + 5][e];
            u16 x6 = hl[u * 8 + 6][e], x7 = hl[u * 8 + 7][e];
            psum += __uint_as_float((u32)x0 << 16) + __uint_as_float((u32)x1 << 16)
                  + __uint_as_float((u32)x2 << 16) + __uint_as_float((u32)x3 << 16)
                  + __uint_as_float((u32)x4 << 16) + __uint_as_float((u32)x5 << 16)
                  + __uint_as_float((u32)x6 << 16) + __uint_as_float((u32)x7 << 16);
            u32 p0 = (u32)x0 | ((u32)x1 << 16), p1 = (u32)x2 | ((u32)x3 << 16);
            u32 p2 = (u32)x4 | ((u32)x5 << 16), p3 = (u32)x6 | ((u32)x7 << 16);
            *(uint4*)(ob + (size_t)(u * 64 + e) * 8) = make_uint4(p0, p1, p2, p3);
        }
        red[(t >> 6) * 64 + e] = psum;
        __syncthreads();
        if (t < 64) {
            float sum = red[t] + red[64 + t] + red[128 + t] + red[192 + t];
            PApart[(size_t)((jc * 2 + half) * 32 + b) * 64 + t] = sum;
        }
        return;
    }

    // ---- M planes: {M1-M0, M2-M0, M0-M1-M2+M3, M0} per dir
    for (int i = t; i < 8192; i += 256) {
        const float* M = (i < 4096) ? Min : Mout;
        int idx = i & 4095;
        float m0 = M[idx], m1 = M[4096 + idx], m2 = M[8192 + idx], m3 = M[12288 + idx];
        u16* o = Mws + (size_t)(i >> 12) * 16384;
        o[idx]         = f2bf(m1 - m0);
        o[4096 + idx]  = f2bf(m2 - m0);
        o[8192 + idx]  = f2bf(m0 - m1 - m2 + m3);
        o[12288 + idx] = f2bf(m0);
    }
}

// ------------------------------------------------------------------ K2: main
__global__ __launch_bounds__(256) void ggnn_main(
    const u32* __restrict__ adjP, const u32* __restrict__ adjPT,
    const u16* __restrict__ Hws, const u16* __restrict__ Mws,
    const float* __restrict__ PApart, const float* __restrict__ bias,
    float* __restrict__ out)
{
    __shared__ u16 Sb[16][16][72];   // per-wave slots w*4+p (p=3 -> PA plane)

    const int t = threadIdx.x;
    const int w = t >> 6;
    const int ln = t & 15, qd = (t & 63) >> 4, qd2 = qd >> 1;
    const int shamt = (qd & 1) * 16;
    const int bid = blockIdx.x;
    const int dir = bid & 1;                 // interleave dirs: share H tile in L2
    const int r2 = bid >> 1;
    const int b = r2 >> 4, it = r2 & 15;

    const u32* Adir = dir ? adjPT : adjP;
    f32x4 acc[3][4];
    #pragma unroll
    for (int p = 0; p < 3; ++p)
        #pragma unroll
        for (int nt = 0; nt < 4; ++nt) acc[p][nt] = (f32x4){0.f, 0.f, 0.f, 0.f};

    for (int jc = 0; jc < 4; ++jc) {
        const u32* at = Adir + (size_t)((b * 4 + jc) * 16 + it) * 1024;
        const u16* ht = Hws + (size_t)(b * 4 + jc) * 16384;

        uint4 Ar[4];
        #pragma unroll
        for (int u = 0; u < 4; ++u)
            Ar[u] = *(const uint4*)(at + (u * 64 + w * 16 + ln) * 4);

        #pragma unroll
        for (int ks = 0; ks < 8; ++ks) {
            bf16x8 bf[4];
            #pragma unroll
            for (int nt = 0; nt < 4; ++nt)
                bf[nt] = *(const bf16x8*)(ht + (size_t)((ks * 4 + qd) * 64 + nt * 16 + ln) * 8);

            uint4 Q = Ar[ks >> 1];
            u32 a = (ks & 1) ? (qd2 ? Q.w : Q.z) : (qd2 ? Q.y : Q.x);
            u32 f = (a >> shamt) & 0xFFFFu;
            u32 x0 = f & 0x5555u;
            u32 x1 = (f >> 1) & 0x5555u;
            u32 xt = x0 & x1;

            union { u32 u[4]; bf16x8 v; } A0, A1, AT;
            #pragma unroll
            for (int wd = 0; wd < 4; ++wd) {
                A0.u[wd] = oh2(x0 >> (4 * wd));
                A1.u[wd] = oh2(x1 >> (4 * wd));
                AT.u[wd] = oh2(xt >> (4 * wd));
            }
            #pragma unroll
            for (int nt = 0; nt < 4; ++nt) {
                acc[0][nt] = __builtin_amdgcn_mfma_f32_16x16x32_bf16(A0.v, bf[nt], acc[0][nt], 0, 0, 0);
                acc[1][nt] = __builtin_amdgcn_mfma_f32_16x16x32_bf16(A1.v, bf[nt], acc[1][nt], 0, 0, 0);
                acc[2][nt] = __builtin_amdgcn_mfma_f32_16x16x32_bf16(AT.v, bf[nt], acc[2][nt], 0, 0, 0);
            }
        }
    }

    // P (C-layout regs) -> LDS bf16 per-wave slots; wave-internal, no barrier
    #pragma unroll
    for (int p = 0; p < 3; ++p)
        #pragma unroll
        for (int nt = 0; nt < 4; ++nt)
            #pragma unroll
            for (int r = 0; r < 4; ++r)
                Sb[w * 4 + p][qd * 4 + r][nt * 16 + ln] = f2bf(acc[p][nt][r]);

    // plane 3: S3[i][e] = PA[e] (sum of 8 per-chunk partials)
    {
        const int lane64 = t & 63;
        float paf = 0.f;
        #pragma unroll
        for (int jcp = 0; jcp < 8; ++jcp)
            paf += PApart[(size_t)(jcp * 32 + b) * 64 + lane64];
        u16 pab = f2bf(paf);
        #pragma unroll
        for (int i = 0; i < 16; ++i)
            Sb[w * 4 + 3][i][lane64] = pab;
    }

    const int dofs = dir * 64;
    f32x4 acc2[4];
    #pragma unroll
    for (int dt = 0; dt < 4; ++dt) {
        float v = bias[dofs + dt * 16 + ln];
        acc2[dt] = (f32x4){v, v, v, v};
    }
    const u16* Mb = Mws + (size_t)dir * 16384;   // [4][64][64]
    #pragma unroll
    for (int p = 0; p < 4; ++p) {
        #pragma unroll
        for (int ks2 = 0; ks2 < 2; ++ks2) {
            bf16x8 af = *(const bf16x8*)&Sb[w * 4 + p][ln][ks2 * 32 + qd * 8];
            #pragma unroll
            for (int dt = 0; dt < 4; ++dt) {
                bf16x8 mf = *(const bf16x8*)(Mb + (size_t)(p * 64 + dt * 16 + ln) * 64
                                             + ks2 * 32 + qd * 8);
                acc2[dt] = __builtin_amdgcn_mfma_f32_16x16x32_bf16(af, mf, acc2[dt], 0, 0, 0);
            }
        }
    }
    #pragma unroll
    for (int dt = 0; dt < 4; ++dt)
        #pragma unroll
        for (int r = 0; r < 4; ++r)
            out[((size_t)b * NN + it * 64 + w * 16 + qd * 4 + r) * 128
                + dofs + dt * 16 + ln] = acc2[dt][r];
}

} // namespace

extern "C" void kernel_launch(void* const* d_in, const int* in_sizes, int n_in,
                              void* d_out, int out_size, void* d_ws, size_t ws_size,
                              hipStream_t stream) {
    (void)in_sizes; (void)n_in; (void)out_size; (void)ws_size;
    const float* h    = (const float*)d_in[0];   // [32,1024,64] f32
    const int*   adj  = (const int*)d_in[1];     // [32,1024,1024] i32
    const float* Min  = (const float*)d_in[2];   // [4,64,64] f32
    const float* Mout = (const float*)d_in[3];   // [4,64,64] f32
    const float* bias = (const float*)d_in[4];   // [128] f32
    float* out = (float*)d_out;                  // [32,1024,128] f32

    char* ws = (char*)d_ws;
    u32* adjP     = (u32*)(ws + 0);              // 8 MB
    u32* adjPT    = (u32*)(ws + 8388608);        // 8 MB
    u16* Hws      = (u16*)(ws + 16777216);       // 4 MB
    float* PApart = (float*)(ws + 20971520);     // 64 KB [8][32][64]
    u16* Mws      = (u16*)(ws + 21037056);       // 64 KB [2][4][64][64]

    prep_all<<<2305, 256, 0, stream>>>(adj, h, Min, Mout, adjP, adjPT, Hws, PApart, Mws);
    ggnn_main<<<1024, 256, 0, stream>>>(adjP, adjPT, Hws, Mws, PApart, bias, out);
}